// Round 14
// baseline (263.664 us; speedup 1.0000x reference)
//
#include <hip/hip_runtime.h>

typedef __attribute__((ext_vector_type(8))) __bf16 bf16x8;
typedef __attribute__((ext_vector_type(4))) float f32x4;
typedef unsigned int u32;
typedef unsigned long long u64;
typedef unsigned short u16;

#define NB 131072   // batch
#define TPB 4       // row-tiles per block (grid 512, 2 blocks/CU)

__device__ __forceinline__ u16 f2bf(float f) {
  unsigned int u = __builtin_bit_cast(unsigned int, f);
  u += 0x7fffu + ((u >> 16) & 1u);
  return (u16)(u >> 16);
}

// pack 2 f32 -> 2 bf16 in one VALU op (RTNE on gfx950; verified R6-R13)
__device__ __forceinline__ u32 cvt_pk(float lo, float hi) {
  u32 r;
  asm("v_cvt_pk_bf16_f32 %0, %1, %2" : "=v"(r) : "v"(lo), "v"(hi));
  return r;
}

// ---------------- prep: bf16 frag-ordered weights + per-pair fused bias ----------------
// ws layout: W1f @0 (64KB), W2f @65536 (128KB), Whf @196608 (64KB), b1p @262144 (3KB)
__global__ void prep_kernel(const float* __restrict__ W1, const float* __restrict__ b1,
                            const float* __restrict__ W2,
                            const float* __restrict__ Wm, const float* __restrict__ Wv,
                            u16* __restrict__ W1f, u16* __restrict__ W2f,
                            u16* __restrict__ Whf, float* __restrict__ b1p) {
  int tid = blockIdx.x * 256 + threadIdx.x;
  int NT = gridDim.x * 256;
  for (int i = tid; i < 32768; i += NT) {   // W1f: frag f = kf*16+nf
    int j = i & 7, lane = (i >> 3) & 63, f = i >> 9;
    int nf = f & 15, kf = f >> 4;
    int n = nf * 16 + (lane & 15);
    int k = kf * 32 + 8 * (lane >> 4) + j;
    W1f[i] = f2bf(W1[k * 256 + n]);
  }
  for (int i = tid; i < 65536; i += NT) {   // W2f: f = kf*16+nf
    int j = i & 7, lane = (i >> 3) & 63, f = i >> 9;
    int nf = f & 15, kf = f >> 4;
    int n = nf * 16 + (lane & 15);
    int k = kf * 32 + 8 * (lane >> 4) + j;
    W2f[i] = f2bf(W2[k * 256 + n]);
  }
  for (int i = tid; i < 32768; i += NT) {   // Whf = [Wm | Wv]: f = kf*8+nf
    int j = i & 7, lane = (i >> 3) & 63, f = i >> 9;
    int nf = f & 7, kf = f >> 3;
    int n = nf * 16 + (lane & 15);
    int k = kf * 32 + 8 * (lane >> 4) + j;
    Whf[i] = f2bf(n < 64 ? Wm[k * 64 + n] : Wv[k * 64 + (n - 64)]);
  }
  if (tid < 768) {                          // pairs (0,1),(0,2),(1,2) -> W1 rows {0,4},{0,5},{1,5}
    int p = tid >> 8, h = tid & 255;
    const int r1[3] = {0, 0, 1};
    const int r2[3] = {4, 5, 5};
    b1p[tid] = b1[h] + W1[r1[p] * 256 + h] + W1[r2[p] * 256 + h];
  }
}

// ---- fused encoder: frag-linear LDS, 80 KB (2 blocks/CU), swapped MFMA, 4 waves/SIMD ----
// LDS activation layout: frag (kf,bf) at (kf*4+bf)*1024, entry lane*16 holds
// k = kf*32 + (lane>>4)*8 + j, batch = bf*16 + (lane&15). Reads = base + lane*16 (0-conflict).
__global__ __launch_bounds__(512, 4) void fused_kernel(
    const float* __restrict__ init_s, const float* __restrict__ cur_s,
    const float* __restrict__ emb,
    const u16* __restrict__ W1f, const u16* __restrict__ W2f,
    const u16* __restrict__ Whf,
    const float* __restrict__ b1p, const float* __restrict__ b2,
    const float* __restrict__ bm, const float* __restrict__ bv,
    float* __restrict__ out) {
  extern __shared__ char smem[];
  char* inp = smem;             // 16 frags (kf<4, bf<4)  = 16 KB
  char* x1  = smem + 16384;     // 32 frags (kf<8, bf<4)  = 32 KB
  char* x2  = smem + 49152;     // 32 frags (kf<8, bf<4)  = 32 KB   total 80 KB exact
  char* ost = x1;               // [64 batch][128 hcol] f32 swizzled, aliases x1 (dead by heads)

  const int t = threadIdx.x;
  const int lane = t & 63;
  const int wave = t >> 6;          // 0..7: n-group for L1/L2 (32 cols)
  const int ql = lane & 15, qw = lane >> 4;
  const int rh = wave >> 2;         // heads: row half (32 rows)
  const int hg = wave & 3;          // heads: col group (32 cols)
  const int le16 = lane * 16;
  // writeback slot within destination frag pair (see header comment)
  const int wofs = (qw >> 1) * 256 + ql * 16 + (qw & 1) * 8;

  // ---- weight fragments (A-operand after swap); compiler balances residency ----
  bf16x8 w1r[4][2];
#pragma unroll
  for (int kf = 0; kf < 4; ++kf)
#pragma unroll
    for (int ni = 0; ni < 2; ++ni)
      w1r[kf][ni] = *(const bf16x8*)(W1f + (size_t)((kf * 16 + wave * 2 + ni) * 64 + lane) * 8);
  bf16x8 w2r[8][2];
#pragma unroll
  for (int kf = 0; kf < 8; ++kf)
#pragma unroll
    for (int ni = 0; ni < 2; ++ni)
      w2r[kf][ni] = *(const bf16x8*)(W2f + (size_t)((kf * 16 + wave * 2 + ni) * 64 + lane) * 8);
  bf16x8 whr[8][2];   // heads row-split: cols [hg*32,+32)
#pragma unroll
  for (int kf = 0; kf < 8; ++kf)
#pragma unroll
    for (int ni = 0; ni < 2; ++ni)
      whr[kf][ni] = *(const bf16x8*)(Whf + (size_t)((kf * 8 + hg * 2 + ni) * 64 + lane) * 8);

  // head bias: col = hg*32 + ni*16 + qw*4 (4 consecutive; never straddles 64)
  f32x4 hb[2];
#pragma unroll
  for (int ni = 0; ni < 2; ++ni) {
    int hn = hg * 32 + ni * 16 + qw * 4;
    hb[ni] = (hn < 64) ? *(const f32x4*)(bm + hn) : *(const f32x4*)(bv + hn - 64);
  }

  const int IA[3] = {0, 1, 2};
  const int IB[3] = {3, 5, 7};
  const int IC[3] = {4, 6, 8};

  // ---- helpers ----
  auto stage_emb = [&](int b0n) {
    for (int i = t; i < 64 * 29; i += 512) {
      int r = i / 29, c4 = i - r * 29;
      const f32x4 v = __builtin_nontemporal_load((const f32x4*)(emb + (size_t)(b0n + r) * 116 + c4 * 4));
      u64 pk = (u64)cvt_pk(v[0], v[1]) | ((u64)cvt_pk(v[2], v[3]) << 32);
      int k0 = 12 + 4 * c4;   // inp col of first elem (mult of 4, never crosses 8-group)
      int a = ((k0 >> 5) * 4 + (r >> 4)) * 1024 + (((k0 >> 3) & 3) * 16 + (r & 15)) * 16 + (k0 & 4) * 2;
      *(u64*)(inp + a) = pk;
    }
  };
  auto stage_scols = [&](int b0n, int np) {
    if (t < 64) {
      const float* isr = init_s + (size_t)(b0n + t) * 9;
      const float* csr = cur_s + (size_t)(b0n + t) * 9;
      int eb = (t >> 4) * 1024 + (t & 15) * 16;        // frag (0, t/16), entry t%16
      *(u32*)(inp + eb + 12)  = cvt_pk(isr[IA[np]], isr[IB[np]]);  // cols 6,7
      *(u32*)(inp + eb + 256) = cvt_pk(isr[IC[np]], csr[IA[np]]);  // cols 8,9
      *(u32*)(inp + eb + 260) = cvt_pk(csr[IB[np]], csr[IC[np]]);  // cols 10,11
    }
  };
  auto do_export = [&](int s) {  // ost -> out (NT, full 256B rows)
    const int pe = s % 3;
    const int b0e = (blockIdx.x * TPB + s / 3) * 64;
    for (int i = t; i < 64 * 32; i += 512) {
      int r = i >> 5, c4 = i & 31;
      f32x4 v = *(const f32x4*)(ost + r * 512 + ((c4 * 16) ^ ((r & 7) << 4)));
      size_t off;
      if (c4 < 16)
        off = ((size_t)pe * NB + b0e + r) * 64 + (size_t)c4 * 4;
      else
        off = (size_t)3 * NB * 64 + ((size_t)pe * NB + b0e + r) * 64 + (size_t)(c4 - 16) * 4;
      __builtin_nontemporal_store(v, (f32x4*)(out + off));
    }
  };

  // ---- prologue: zeros for one-hot cols 0..5 (persist), stage step 0 ----
  if (t < 64) {
    int eb = (t >> 4) * 1024 + (t & 15) * 16;
    *(u64*)(inp + eb) = 0ull;        // cols 0-3
    *(u32*)(inp + eb + 8) = 0u;      // cols 4,5
  }
  {
    const int b00 = blockIdx.x * TPB * 64;
    stage_emb(b00);
    stage_scols(b00, 0);
  }
  __syncthreads();

#pragma unroll 1
  for (int step = 0; step < 3 * TPB; ++step) {
    // ---- L1: inp -> x1; wave n-cols [wave*32,+32) ----
    {
      const int p1 = step % 3;
      f32x4 acc[4][2];
#pragma unroll
      for (int ni = 0; ni < 2; ++ni) {
        f32x4 bb = *(const f32x4*)(b1p + p1 * 256 + wave * 32 + ni * 16 + qw * 4);
#pragma unroll
        for (int bf = 0; bf < 4; ++bf) acc[bf][ni] = bb;
      }
#pragma unroll
      for (int kf = 0; kf < 4; ++kf) {
        bf16x8 b[4];
#pragma unroll
        for (int bf = 0; bf < 4; ++bf)
          b[bf] = *(const bf16x8*)(inp + ((kf * 4 + bf) << 10) + le16);
#pragma unroll
        for (int ni = 0; ni < 2; ++ni)
#pragma unroll
          for (int bf = 0; bf < 4; ++bf)
            acc[bf][ni] = __builtin_amdgcn_mfma_f32_16x16x32_bf16(w1r[kf][ni], b[bf], acc[bf][ni], 0, 0, 0);
      }
#pragma unroll
      for (int bf = 0; bf < 4; ++bf)
#pragma unroll
        for (int ni = 0; ni < 2; ++ni) {
          f32x4 v = acc[bf][ni];
          u64 pk = (u64)cvt_pk(fmaxf(v[0], 0.f), fmaxf(v[1], 0.f))
                 | ((u64)cvt_pk(fmaxf(v[2], 0.f), fmaxf(v[3], 0.f)) << 32);
          *(u64*)(x1 + ((wave * 4 + bf) << 10) + ni * 512 + wofs) = pk;
        }
    }
    __syncthreads();  // BAR1: x1 ready

    // ---- L2: x1 -> x2 ----
    {
      f32x4 acc[4][2];
#pragma unroll
      for (int ni = 0; ni < 2; ++ni) {
        f32x4 bb = *(const f32x4*)(b2 + wave * 32 + ni * 16 + qw * 4);
#pragma unroll
        for (int bf = 0; bf < 4; ++bf) acc[bf][ni] = bb;
      }
#pragma unroll
      for (int kf = 0; kf < 8; ++kf) {
        bf16x8 b[4];
#pragma unroll
        for (int bf = 0; bf < 4; ++bf)
          b[bf] = *(const bf16x8*)(x1 + ((kf * 4 + bf) << 10) + le16);
#pragma unroll
        for (int ni = 0; ni < 2; ++ni)
#pragma unroll
          for (int bf = 0; bf < 4; ++bf)
            acc[bf][ni] = __builtin_amdgcn_mfma_f32_16x16x32_bf16(w2r[kf][ni], b[bf], acc[bf][ni], 0, 0, 0);
      }
#pragma unroll
      for (int bf = 0; bf < 4; ++bf)
#pragma unroll
        for (int ni = 0; ni < 2; ++ni) {
          f32x4 v = acc[bf][ni];
          u64 pk = (u64)cvt_pk(fmaxf(v[0], 0.f), fmaxf(v[1], 0.f))
                 | ((u64)cvt_pk(fmaxf(v[2], 0.f), fmaxf(v[3], 0.f)) << 32);
          *(u64*)(x2 + ((wave * 4 + bf) << 10) + ni * 512 + wofs) = pk;
        }
    }
    __syncthreads();  // BAR2: x2 ready (x1/ost now dead)

    // ---- heads: x2 -> ost; wave = (row-half rh, col-group hg) ----
    {
      f32x4 hacc[2][2];
#pragma unroll
      for (int bf = 0; bf < 2; ++bf)
#pragma unroll
        for (int ni = 0; ni < 2; ++ni) hacc[bf][ni] = hb[ni];
#pragma unroll
      for (int kf = 0; kf < 8; ++kf) {
        bf16x8 b[2];
#pragma unroll
        for (int bf = 0; bf < 2; ++bf)
          b[bf] = *(const bf16x8*)(x2 + ((kf * 4 + rh * 2 + bf) << 10) + le16);
#pragma unroll
        for (int ni = 0; ni < 2; ++ni)
#pragma unroll
          for (int bf = 0; bf < 2; ++bf)
            hacc[bf][ni] = __builtin_amdgcn_mfma_f32_16x16x32_bf16(whr[kf][ni], b[bf], hacc[bf][ni], 0, 0, 0);
      }
#pragma unroll
      for (int bf = 0; bf < 2; ++bf)
#pragma unroll
        for (int ni = 0; ni < 2; ++ni) {
          int row = rh * 32 + bf * 16 + ql;                 // batch
          int byte = hg * 128 + ni * 64 + qw * 16;          // hcol*4
          *(f32x4*)(ost + row * 512 + (byte ^ ((row & 7) << 4))) = hacc[bf][ni];
        }
    }
    __syncthreads();  // BAR3: ost ready

    // ---- export(step) + stage(step+1); inp is free (L1 done), ost consumed by BAR4 ----
    do_export(step);
    if (step + 1 < 3 * TPB) {
      const int s1 = step + 1;
      const int b0n = (blockIdx.x * TPB + s1 / 3) * 64;
      if (s1 % 3 == 0) stage_emb(b0n);   // tile boundary: new embeddings
      stage_scols(b0n, s1 % 3);
    }
    __syncthreads();  // BAR4: ost reads done (next L1 writes x1=ost); inp ready
  }
}

extern "C" void kernel_launch(void* const* d_in, const int* in_sizes, int n_in,
                              void* d_out, int out_size, void* d_ws, size_t ws_size,
                              hipStream_t stream) {
  (void)in_sizes; (void)n_in; (void)out_size; (void)ws_size;
  const float* init_s = (const float*)d_in[0];
  const float* cur_s  = (const float*)d_in[1];
  const float* emb    = (const float*)d_in[2];
  const float* W1 = (const float*)d_in[3];
  const float* b1 = (const float*)d_in[4];
  const float* W2 = (const float*)d_in[5];
  const float* b2 = (const float*)d_in[6];
  const float* Wm = (const float*)d_in[7];
  const float* bm = (const float*)d_in[8];
  const float* Wv = (const float*)d_in[9];
  const float* bv = (const float*)d_in[10];

  u16* W1f = (u16*)d_ws;
  u16* W2f = (u16*)((char*)d_ws + 65536);
  u16* Whf = (u16*)((char*)d_ws + 196608);
  float* b1p = (float*)((char*)d_ws + 262144);

  prep_kernel<<<128, 256, 0, stream>>>(W1, b1, W2, Wm, Wv, W1f, W2f, Whf, b1p);

  const int lds_bytes = 16384 + 32768 + 32768;  // 80 KB exact -> 2 blocks/CU
  (void)hipFuncSetAttribute((const void*)fused_kernel,
                            hipFuncAttributeMaxDynamicSharedMemorySize, lds_bytes);
  fused_kernel<<<NB / (64 * TPB), 512, lds_bytes, stream>>>(init_s, cur_s, emb, W1f, W2f, Whf,
                                                            b1p, b2, bm, bv, (float*)d_out);
}

// Round 15
// 119.799 us; speedup vs baseline: 2.2009x; 2.2009x over previous
//
#include <hip/hip_runtime.h>

typedef __attribute__((ext_vector_type(8))) __bf16 bf16x8;
typedef __attribute__((ext_vector_type(4))) float f32x4;
typedef unsigned int u32;
typedef unsigned long long u64;
typedef unsigned short u16;

#define NB 131072   // batch
#define TPB 8       // row-tiles per block (grid 256, persistent)

__device__ __forceinline__ u16 f2bf(float f) {
  unsigned int u = __builtin_bit_cast(unsigned int, f);
  u += 0x7fffu + ((u >> 16) & 1u);
  return (u16)(u >> 16);
}

// pack 2 f32 -> 2 bf16 in one VALU op (RTNE on gfx950; verified R6-R13)
__device__ __forceinline__ u32 cvt_pk(float lo, float hi) {
  u32 r;
  asm("v_cvt_pk_bf16_f32 %0, %1, %2" : "=v"(r) : "v"(lo), "v"(hi));
  return r;
}

// ---------------- prep: bf16 frag-ordered weights + per-pair fused bias ----------------
// ws layout: W1f @0 (64KB), W2f @65536 (128KB), Whf @196608 (64KB), b1p @262144 (3KB)
__global__ void prep_kernel(const float* __restrict__ W1, const float* __restrict__ b1,
                            const float* __restrict__ W2,
                            const float* __restrict__ Wm, const float* __restrict__ Wv,
                            u16* __restrict__ W1f, u16* __restrict__ W2f,
                            u16* __restrict__ Whf, float* __restrict__ b1p) {
  int tid = blockIdx.x * 256 + threadIdx.x;
  int NT = gridDim.x * 256;
  for (int i = tid; i < 32768; i += NT) {   // W1f: frag f = kf*16+nf
    int j = i & 7, lane = (i >> 3) & 63, f = i >> 9;
    int nf = f & 15, kf = f >> 4;
    int n = nf * 16 + (lane & 15);
    int k = kf * 32 + 8 * (lane >> 4) + j;
    W1f[i] = f2bf(W1[k * 256 + n]);
  }
  for (int i = tid; i < 65536; i += NT) {   // W2f: f = kf*16+nf
    int j = i & 7, lane = (i >> 3) & 63, f = i >> 9;
    int nf = f & 15, kf = f >> 4;
    int n = nf * 16 + (lane & 15);
    int k = kf * 32 + 8 * (lane >> 4) + j;
    W2f[i] = f2bf(W2[k * 256 + n]);
  }
  for (int i = tid; i < 32768; i += NT) {   // Whf = [Wm | Wv]: f = kf*8+nf
    int j = i & 7, lane = (i >> 3) & 63, f = i >> 9;
    int nf = f & 7, kf = f >> 3;
    int n = nf * 16 + (lane & 15);
    int k = kf * 32 + 8 * (lane >> 4) + j;
    Whf[i] = f2bf(n < 64 ? Wm[k * 64 + n] : Wv[k * 64 + (n - 64)]);
  }
  if (tid < 768) {                          // pairs (0,1),(0,2),(1,2) -> W1 rows {0,4},{0,5},{1,5}
    int p = tid >> 8, h = tid & 255;
    const int r1[3] = {0, 0, 1};
    const int r2[3] = {4, 5, 5};
    b1p[tid] = b1[h] + W1[r1[p] * 256 + h] + W1[r2[p] * 256 + h];
  }
}

// ---- fused encoder: frag-linear LDS, 2-barrier pipeline, swapped MFMA, 1 block/CU ----
// LDS activation layout: frag (kf,bf) at (kf*4+bf)*1024, entry lane*16 holds
// k = kf*32 + (lane>>4)*8 + j, batch = bf*16 + (lane&15). Reads = base + lane*16 (0-conflict).
__global__ __launch_bounds__(512, 2) void fused_kernel(
    const float* __restrict__ init_s, const float* __restrict__ cur_s,
    const float* __restrict__ emb,
    const u16* __restrict__ W1f, const u16* __restrict__ W2f,
    const u16* __restrict__ Whf,
    const float* __restrict__ b1p, const float* __restrict__ b2,
    const float* __restrict__ bm, const float* __restrict__ bv,
    float* __restrict__ out) {
  extern __shared__ char smem[];
  char* inp = smem;             // 16 frags (kf<4, bf<4)  = 16 KB
  char* x1  = smem + 16384;     // 32 frags (kf<8, bf<4)  = 32 KB
  char* x2  = smem + 49152;     // 32 frags (kf<8, bf<4)  = 32 KB
  char* ost = smem + 81920;     // [64 batch][128 hcol] f32 swizzled (32 KB)

  const int t = threadIdx.x;
  const int lane = t & 63;
  const int wave = t >> 6;          // 0..7: n-group for L1/L2 (32 cols)
  const int ql = lane & 15, qw = lane >> 4;
  const int rh = wave >> 2;         // heads: row half (32 rows)
  const int hg = wave & 3;          // heads: col group (32 cols)
  const int le16 = lane * 16;
  // writeback slot within destination frag pair (see header comment)
  const int wofs = (qw >> 1) * 256 + ql * 16 + (qw & 1) * 8;

  // ---- weight fragments (A-operand after swap); compiler balances residency ----
  bf16x8 w1r[4][2];
#pragma unroll
  for (int kf = 0; kf < 4; ++kf)
#pragma unroll
    for (int ni = 0; ni < 2; ++ni)
      w1r[kf][ni] = *(const bf16x8*)(W1f + (size_t)((kf * 16 + wave * 2 + ni) * 64 + lane) * 8);
  bf16x8 w2r[8][2];
#pragma unroll
  for (int kf = 0; kf < 8; ++kf)
#pragma unroll
    for (int ni = 0; ni < 2; ++ni)
      w2r[kf][ni] = *(const bf16x8*)(W2f + (size_t)((kf * 16 + wave * 2 + ni) * 64 + lane) * 8);
  bf16x8 whr[8][2];   // heads row-split: cols [hg*32,+32)
#pragma unroll
  for (int kf = 0; kf < 8; ++kf)
#pragma unroll
    for (int ni = 0; ni < 2; ++ni)
      whr[kf][ni] = *(const bf16x8*)(Whf + (size_t)((kf * 8 + hg * 2 + ni) * 64 + lane) * 8);

  // head bias: col = hg*32 + ni*16 + qw*4 (4 consecutive; never straddles 64)
  f32x4 hb[2];
#pragma unroll
  for (int ni = 0; ni < 2; ++ni) {
    int hn = hg * 32 + ni * 16 + qw * 4;
    hb[ni] = (hn < 64) ? *(const f32x4*)(bm + hn) : *(const f32x4*)(bv + hn - 64);
  }

  const int IA[3] = {0, 1, 2};
  const int IB[3] = {3, 5, 7};
  const int IC[3] = {4, 6, 8};

  // ---- helpers ----
  auto stage_emb = [&](int b0n) {
    for (int i = t; i < 64 * 29; i += 512) {
      int r = i / 29, c4 = i - r * 29;
      const f32x4 v = __builtin_nontemporal_load((const f32x4*)(emb + (size_t)(b0n + r) * 116 + c4 * 4));
      u64 pk = (u64)cvt_pk(v[0], v[1]) | ((u64)cvt_pk(v[2], v[3]) << 32);
      int k0 = 12 + 4 * c4;   // inp col of first elem (mult of 4, never crosses 8-group)
      int a = ((k0 >> 5) * 4 + (r >> 4)) * 1024 + (((k0 >> 3) & 3) * 16 + (r & 15)) * 16 + (k0 & 4) * 2;
      *(u64*)(inp + a) = pk;
    }
  };
  auto stage_scols = [&](int b0n, int np) {
    if (t < 64) {
      const float* isr = init_s + (size_t)(b0n + t) * 9;
      const float* csr = cur_s + (size_t)(b0n + t) * 9;
      int eb = (t >> 4) * 1024 + (t & 15) * 16;        // frag (0, t/16), entry t%16
      *(u32*)(inp + eb + 12)  = cvt_pk(isr[IA[np]], isr[IB[np]]);  // cols 6,7
      *(u32*)(inp + eb + 256) = cvt_pk(isr[IC[np]], csr[IA[np]]);  // cols 8,9
      *(u32*)(inp + eb + 260) = cvt_pk(csr[IB[np]], csr[IC[np]]);  // cols 10,11
    }
  };
  auto do_l1 = [&](int s) {   // inp -> x1; wave n-cols [wave*32,+32)
    const int p1 = s % 3;
    f32x4 acc[4][2];
#pragma unroll
    for (int ni = 0; ni < 2; ++ni) {
      f32x4 bb = *(const f32x4*)(b1p + p1 * 256 + wave * 32 + ni * 16 + qw * 4);
#pragma unroll
      for (int bf = 0; bf < 4; ++bf) acc[bf][ni] = bb;
    }
    __builtin_amdgcn_s_setprio(1);
#pragma unroll
    for (int kf = 0; kf < 4; ++kf) {
      bf16x8 b[4];
#pragma unroll
      for (int bf = 0; bf < 4; ++bf)
        b[bf] = *(const bf16x8*)(inp + ((kf * 4 + bf) << 10) + le16);
#pragma unroll
      for (int ni = 0; ni < 2; ++ni)
#pragma unroll
        for (int bf = 0; bf < 4; ++bf)
          acc[bf][ni] = __builtin_amdgcn_mfma_f32_16x16x32_bf16(w1r[kf][ni], b[bf], acc[bf][ni], 0, 0, 0);
    }
    __builtin_amdgcn_s_setprio(0);
#pragma unroll
    for (int bf = 0; bf < 4; ++bf)
#pragma unroll
      for (int ni = 0; ni < 2; ++ni) {
        f32x4 v = acc[bf][ni];
        u64 pk = (u64)cvt_pk(fmaxf(v[0], 0.f), fmaxf(v[1], 0.f))
               | ((u64)cvt_pk(fmaxf(v[2], 0.f), fmaxf(v[3], 0.f)) << 32);
        *(u64*)(x1 + ((wave * 4 + bf) << 10) + ni * 512 + wofs) = pk;
      }
  };
  auto do_export = [&](int s) {  // ost -> out (NT, full 256B rows)
    const int pe = s % 3;
    const int b0e = (blockIdx.x * TPB + s / 3) * 64;
    for (int i = t; i < 64 * 32; i += 512) {
      int r = i >> 5, c4 = i & 31;
      f32x4 v = *(const f32x4*)(ost + r * 512 + ((c4 * 16) ^ ((r & 7) << 4)));
      size_t off;
      if (c4 < 16)
        off = ((size_t)pe * NB + b0e + r) * 64 + (size_t)c4 * 4;
      else
        off = (size_t)3 * NB * 64 + ((size_t)pe * NB + b0e + r) * 64 + (size_t)(c4 - 16) * 4;
      __builtin_nontemporal_store(v, (f32x4*)(out + off));
    }
  };

  // ---- prologue: zeros for one-hot cols 0..5 (persist), stage step 0, L1(0) ----
  if (t < 64) {
    int eb = (t >> 4) * 1024 + (t & 15) * 16;
    *(u64*)(inp + eb) = 0ull;        // cols 0-3
    *(u32*)(inp + eb + 8) = 0u;      // cols 4,5
  }
  {
    const int b00 = blockIdx.x * TPB * 64;
    stage_emb(b00);
    stage_scols(b00, 0);
  }
  __syncthreads();
  do_l1(0);
  __syncthreads();

#pragma unroll 1
  for (int step = 0; step < 3 * TPB; ++step) {
    // ================= Phase alpha: L2(step) | export(step-1) | stage(step+1) =================
    {
      f32x4 acc[4][2];
#pragma unroll
      for (int ni = 0; ni < 2; ++ni) {
        f32x4 bb = *(const f32x4*)(b2 + wave * 32 + ni * 16 + qw * 4);
#pragma unroll
        for (int bf = 0; bf < 4; ++bf) acc[bf][ni] = bb;
      }
      __builtin_amdgcn_s_setprio(1);
#pragma unroll
      for (int kf = 0; kf < 8; ++kf) {
        bf16x8 b[4];
#pragma unroll
        for (int bf = 0; bf < 4; ++bf)
          b[bf] = *(const bf16x8*)(x1 + ((kf * 4 + bf) << 10) + le16);
#pragma unroll
        for (int ni = 0; ni < 2; ++ni)
#pragma unroll
          for (int bf = 0; bf < 4; ++bf)
            acc[bf][ni] = __builtin_amdgcn_mfma_f32_16x16x32_bf16(w2r[kf][ni], b[bf], acc[bf][ni], 0, 0, 0);
      }
      __builtin_amdgcn_s_setprio(0);
      // overlapped: export previous pair + stage next pair while MFMAs drain
      if (step > 0) do_export(step - 1);
      if (step + 1 < 3 * TPB) {
        const int s1 = step + 1;
        const int b0n = (blockIdx.x * TPB + s1 / 3) * 64;
        if (s1 % 3 == 0) stage_emb(b0n);   // tile boundary: new embeddings
        stage_scols(b0n, s1 % 3);
      }
#pragma unroll
      for (int bf = 0; bf < 4; ++bf)
#pragma unroll
        for (int ni = 0; ni < 2; ++ni) {
          f32x4 v = acc[bf][ni];
          u64 pk = (u64)cvt_pk(fmaxf(v[0], 0.f), fmaxf(v[1], 0.f))
                 | ((u64)cvt_pk(fmaxf(v[2], 0.f), fmaxf(v[3], 0.f)) << 32);
          *(u64*)(x2 + ((wave * 4 + bf) << 10) + ni * 512 + wofs) = pk;
        }
    }
    __syncthreads();  // BAR A: x2 ready; inp staged; ost consumed

    // ================= Phase beta: heads(step) | L1(step+1) =================
    {
      f32x4 hacc[2][2];
#pragma unroll
      for (int bf = 0; bf < 2; ++bf)
#pragma unroll
        for (int ni = 0; ni < 2; ++ni) hacc[bf][ni] = hb[ni];
      __builtin_amdgcn_s_setprio(1);
#pragma unroll
      for (int kf = 0; kf < 8; ++kf) {
        bf16x8 b[2];
#pragma unroll
        for (int bf = 0; bf < 2; ++bf)
          b[bf] = *(const bf16x8*)(x2 + ((kf * 4 + rh * 2 + bf) << 10) + le16);
#pragma unroll
        for (int ni = 0; ni < 2; ++ni)
#pragma unroll
          for (int bf = 0; bf < 2; ++bf)
            hacc[bf][ni] = __builtin_amdgcn_mfma_f32_16x16x32_bf16(whr[kf][ni], b[bf], hacc[bf][ni], 0, 0, 0);
      }
      __builtin_amdgcn_s_setprio(0);
#pragma unroll
      for (int bf = 0; bf < 2; ++bf)
#pragma unroll
        for (int ni = 0; ni < 2; ++ni) {
          int row = rh * 32 + bf * 16 + ql;                 // batch
          int byte = hg * 128 + ni * 64 + qw * 16;          // hcol*4
          *(f32x4*)(ost + row * 512 + (byte ^ ((row & 7) << 4))) = hacc[bf][ni];
        }
      if (step + 1 < 3 * TPB) do_l1(step + 1);
    }
    __syncthreads();  // BAR B: ost ready; x1 ready for next L2
  }

  do_export(3 * TPB - 1);
}

extern "C" void kernel_launch(void* const* d_in, const int* in_sizes, int n_in,
                              void* d_out, int out_size, void* d_ws, size_t ws_size,
                              hipStream_t stream) {
  (void)in_sizes; (void)n_in; (void)out_size; (void)ws_size;
  const float* init_s = (const float*)d_in[0];
  const float* cur_s  = (const float*)d_in[1];
  const float* emb    = (const float*)d_in[2];
  const float* W1 = (const float*)d_in[3];
  const float* b1 = (const float*)d_in[4];
  const float* W2 = (const float*)d_in[5];
  const float* b2 = (const float*)d_in[6];
  const float* Wm = (const float*)d_in[7];
  const float* bm = (const float*)d_in[8];
  const float* Wv = (const float*)d_in[9];
  const float* bv = (const float*)d_in[10];

  u16* W1f = (u16*)d_ws;
  u16* W2f = (u16*)((char*)d_ws + 65536);
  u16* Whf = (u16*)((char*)d_ws + 196608);
  float* b1p = (float*)((char*)d_ws + 262144);

  prep_kernel<<<128, 256, 0, stream>>>(W1, b1, W2, Wm, Wv, W1f, W2f, Whf, b1p);

  const int lds_bytes = 16384 + 32768 + 32768 + 32768;  // 114688 — 1 block/CU
  (void)hipFuncSetAttribute((const void*)fused_kernel,
                            hipFuncAttributeMaxDynamicSharedMemorySize, lds_bytes);
  fused_kernel<<<NB / (64 * TPB), 512, lds_bytes, stream>>>(init_s, cur_s, emb, W1f, W2f, Whf,
                                                            b1p, b2, bm, bv, (float*)d_out);
}